// Round 9
// baseline (685.310 us; speedup 1.0000x reference)
//
#include <hip/hip_runtime.h>
#include <math.h>

#define K_EMB 1024
#define D_DIM 256
#define T_SZ 2048
#define TOT 16777216        // B*D*T
#define LOSS_OFF 16777216
#define IDX_OFF 16777217
#define NDC 17              // 16 real d-chunks + 1 esq-fold chunk (A-side)
#define THR 0.6f            // ~10 sigma of bf16 score-diff noise -> exact refine

// workspace layout (bytes) — 1,867,776 total
#define WS_EHI  0           //   557,056  E frags [32 kc][17 dc][64 lane] x 16B
#define WS_X2   557056      //   262,144  ||x||^2 per token [65536] f32
#define WS_CAND 819200      // 1,048,576  per-token top3 packed float4 [65536]

// K2 (argmin) LDS layout — 92,160 B -> 1 block/CU
#define SM2_XH  0           // 65,536  X frags for the 128-t tile
#define SM2_X2P 65536       //  2,048  per-thread x^2 partials (512 f32)
#define SM2_RV  67584       // 12,288  top3 vals [8w][4tc][32m][3] f32
#define SM2_RK  79872       // 12,288  top3 keys
#define SM2_TOT 92160

// K3 (finish) LDS layout
#define SM3_Q    0          // 65,792  q overlay [64][257] f32 (conflict-free cols)
#define SM3_IDX  65792      //    256  idx per t
#define SM3_TIEC 66048      //      8  tie count
#define SM3_TIEL 66056      //    512  64 x uint2 tie entries
#define SM3_TOT  66568      // -> 2 blocks/CU

typedef __attribute__((ext_vector_type(8)))  __bf16 bf16x8;
typedef __attribute__((ext_vector_type(8)))  short  s16x8;
typedef __attribute__((ext_vector_type(16))) float  f32x16;

__device__ __forceinline__ unsigned short f2bf(float f) {   // RNE fp32->bf16 bits
    unsigned u = __float_as_uint(f);
    u += 0x7FFFu + ((u >> 16) & 1u);
    return (unsigned short)(u >> 16);
}
__device__ __forceinline__ float bf2f(unsigned short h) {
    return __uint_as_float(((unsigned)h) << 16);
}
// top-3 insert, maximizing, VALUE-ONLY compares (exact-equal scores have
// gap 0 < THR -> routed to exact-fp64 refine which applies the k-tie-break).
__device__ __forceinline__ void ins3(float& v1, int& k1, float& v2, int& k2,
                                     float& v3, int& k3, float v, int k) {
    if (v > v1)      { v3 = v2; k3 = k2; v2 = v1; k2 = k1; v1 = v; k1 = k; }
    else if (v > v2) { v3 = v2; k3 = k2; v2 = v;  k2 = k; }
    else if (v > v3) { v3 = v;  k3 = k; }
}

// --- K0: pre-pack E into MFMA A-frag order (bf16) + loss zero -------------
// frag (kc, dc, lane): A[m=lane&31][kd=(lane>>5)*8+j], k=kc*32+m,
// d=dc*16+(lane>>5)*8+j. dc==16 = esq-fold: slot0=bf16(-esq/2), slot1=residual.
__global__ __launch_bounds__(256) void prepack_kernel(const float* __restrict__ E,
        unsigned short* __restrict__ Ehi, float* __restrict__ loss) {
    if (blockIdx.x == 0 && threadIdx.x == 0) loss[0] = 0.f;
    int gid = blockIdx.x * 256 + threadIdx.x;        // == (kc*17+dc)*64 + lane
    if (gid >= 32 * NDC * 64) return;
    int lane = gid & 63;
    int dc = (gid >> 6) % NDC;
    int kc = gid / (NDC * 64);
    int m = lane & 31, dh = lane >> 5;
    int k = kc * 32 + m;
    unsigned short h8[8];
#pragma unroll
    for (int j = 0; j < 8; ++j) h8[j] = 0;
    if (dc < 16) {
        int d0 = dc * 16 + dh * 8;
        const float* ep = E + (size_t)k * D_DIM + d0;
#pragma unroll
        for (int j = 0; j < 8; ++j) h8[j] = f2bf(ep[j]);
    } else if (dh == 0) {
        const float* er = E + (size_t)k * D_DIM;
        float s0 = 0.f, s1 = 0.f, s2 = 0.f, s3 = 0.f;
        for (int i = 0; i < D_DIM; i += 4) {
            s0 = fmaf(er[i], er[i], s0);
            s1 = fmaf(er[i + 1], er[i + 1], s1);
            s2 = fmaf(er[i + 2], er[i + 2], s2);
            s3 = fmaf(er[i + 3], er[i + 3], s3);
        }
        float v = -0.5f * ((s0 + s1) + (s2 + s3));
        unsigned short h = f2bf(v);
        h8[0] = h;
        h8[1] = f2bf(v - bf2f(h));
    }
    s16x8 hv;
#pragma unroll
    for (int j = 0; j < 8; ++j) hv[j] = (short)h8[j];
    ((s16x8*)Ehi)[gid] = hv;
}

// --- K2: argmin core. grid 512, 512 thr / 8 waves, __launch_bounds__(512,1)
// SPILL FIX, round 2: the 2nd launch_bounds arg behaves as min BLOCKS/CU on
// this stack (R5 arg=4 -> 52 VGPR; R8 arg=2 -> 64+64=128 total, still
// spilling ~100 KB/block). arg=1 caps regs at >=256 under either
// interpretation. Manual operand prefetch stripped (was 40 arch VGPRs of
// pressure); compiler's counted-lgkmcnt scheduling covers LDS->MFMA.
// Wave w owns kc = rnd*8+w over 4 rounds; per 1KB E-frag: 4 MFMAs.
__global__ __launch_bounds__(512, 1) void argmin_kernel(
        const float* __restrict__ X, const unsigned short* __restrict__ Ehi,
        float4* __restrict__ cand, float* __restrict__ x2g) {
    extern __shared__ char smem[];
    unsigned short* xhf = (unsigned short*)(smem + SM2_XH);
    float* x2p = (float*)(smem + SM2_X2P);
    float* redv = (float*)(smem + SM2_RV);
    int*   redk = (int*)(smem + SM2_RK);

    int tid = threadIdx.x;
    int lane = tid & 63;
    int w = tid >> 6;                        // 0..7
    int dhalf = lane >> 5;
    int tile = blockIdx.x;                   // 0..511
    int b = tile >> 4, tg0 = (tile & 15) << 7;

    // ---- stage X tile [128 t][256 d] -> frag-order bf16 + ||x||^2 ----
    {
        int t = tid & 127, dblk = tid >> 7;  // 4 dblk x 64 d
        int tc = t >> 5, m = t & 31;
        const float* xp = X + (size_t)b * ((size_t)D_DIM * T_SZ) + tg0 + t;
        float x2a = 0.f;
#pragma unroll
        for (int g = 0; g < 8; ++g) {
            int d0 = dblk * 64 + g * 8;
            s16x8 hv;
#pragma unroll
            for (int j = 0; j < 8; ++j) {
                float xv = xp[(size_t)(d0 + j) * T_SZ];
                hv[j] = (short)f2bf(xv);
                x2a = fmaf(xv, xv, x2a);
            }
            int fi = (tc * 16 + (d0 >> 4)) * 64 + ((d0 >> 3) & 1) * 32 + m;
            ((s16x8*)xhf)[fi] = hv;
        }
        x2p[tid] = x2a;
    }
    __syncthreads();

    const s16x8* ehp = (const s16x8*)Ehi;
    const s16x8* bhf = (const s16x8*)xhf;

    s16x8 bfold = {0, 0, 0, 0, 0, 0, 0, 0};
    if (dhalf == 0) { bfold[0] = (short)0x3F80; bfold[1] = (short)0x3F80; }
    bf16x8 bh_fold = __builtin_bit_cast(bf16x8, bfold);

    float v1s[4], v2s[4], v3s[4];
    int k1s[4], k2s[4], k3s[4];
#pragma unroll
    for (int j = 0; j < 4; ++j) { v1s[j] = -INFINITY; v2s[j] = -INFINITY;
                                  v3s[j] = -INFINITY; k1s[j] = 0; k2s[j] = 0;
                                  k3s[j] = 0; }

#pragma unroll 1
    for (int rnd = 0; rnd < 4; ++rnd) {
        int kc = rnd * 8 + w;                // this wave's codebook tile
        f32x16 acc[4];
#pragma unroll
        for (int tc = 0; tc < 4; ++tc)
#pragma unroll
            for (int i = 0; i < 16; ++i) acc[tc][i] = 0.f;

        size_t ab = (size_t)kc * NDC * 64 + lane;
        s16x8 nh = ehp[ab];                  // depth-1 rotating E prefetch

#pragma unroll 1
        for (int dc = 0; dc < 16; ++dc) {
            bf16x8 ah = __builtin_bit_cast(bf16x8, nh);
            nh = ehp[ab + (size_t)(dc + 1) * 64];    // dc==15 -> fold chunk
#pragma unroll
            for (int tc = 0; tc < 4; ++tc) {
                bf16x8 bh = __builtin_bit_cast(bf16x8, bhf[(tc * 16 + dc) * 64 + lane]);
                acc[tc] = __builtin_amdgcn_mfma_f32_32x32x16_bf16(ah, bh, acc[tc], 0, 0, 0);
            }
        }
        {   // esq-fold chunk (dc==16, in nh): B constant 1.0 in kd slots 0,1
            bf16x8 ah = __builtin_bit_cast(bf16x8, nh);
#pragma unroll
            for (int tc = 0; tc < 4; ++tc)
                acc[tc] = __builtin_amdgcn_mfma_f32_32x32x16_bf16(
                              ah, bh_fold, acc[tc], 0, 0, 0);
        }
        // scan acc -> per-tc running top3
        int kb = kc * 32 + 4 * dhalf;
#pragma unroll
        for (int tc = 0; tc < 4; ++tc)
#pragma unroll
            for (int ri = 0; ri < 16; ++ri) {
                int kk = kb + (ri & 3) + 8 * (ri >> 2);
                ins3(v1s[tc], k1s[tc], v2s[tc], k2s[tc],
                     v3s[tc], k3s[tc], acc[tc][ri], kk);
            }
    }

    // merge lane^32 partner (same t, complementary k rows), store to LDS
#pragma unroll
    for (int tc = 0; tc < 4; ++tc) {
        float pv1 = __shfl_xor(v1s[tc], 32, 64); int pk1 = __shfl_xor(k1s[tc], 32, 64);
        float pv2 = __shfl_xor(v2s[tc], 32, 64); int pk2 = __shfl_xor(k2s[tc], 32, 64);
        float pv3 = __shfl_xor(v3s[tc], 32, 64); int pk3 = __shfl_xor(k3s[tc], 32, 64);
        ins3(v1s[tc], k1s[tc], v2s[tc], k2s[tc], v3s[tc], k3s[tc], pv1, pk1);
        ins3(v1s[tc], k1s[tc], v2s[tc], k2s[tc], v3s[tc], k3s[tc], pv2, pk2);
        ins3(v1s[tc], k1s[tc], v2s[tc], k2s[tc], v3s[tc], k3s[tc], pv3, pk3);
        if (dhalf == 0) {
            int base = ((w * 4 + tc) * 32 + (lane & 31)) * 3;
            redv[base]     = v1s[tc]; redk[base]     = k1s[tc];
            redv[base + 1] = v2s[tc]; redk[base + 1] = k2s[tc];
            redv[base + 2] = v3s[tc]; redk[base + 2] = k3s[tc];
        }
    }
    __syncthreads();

    // per-t reduce across 8 waves -> packed top3 + ||x||^2 to global
    if (tid < 128) {
        int t = tid, tc = t >> 5, m = t & 31;
        float v1 = -INFINITY, v2 = -INFINITY, v3 = -INFINITY;
        int k1 = 0, k2 = 0, k3 = 0;
#pragma unroll
        for (int ww = 0; ww < 8; ++ww) {
            int base = ((ww * 4 + tc) * 32 + m) * 3;
            ins3(v1, k1, v2, k2, v3, k3, redv[base], redk[base]);
            ins3(v1, k1, v2, k2, v3, k3, redv[base + 1], redk[base + 1]);
            ins3(v1, k1, v2, k2, v3, k3, redv[base + 2], redk[base + 2]);
        }
        float x2 = 0.f;
#pragma unroll
        for (int i = 0; i < 4; ++i) x2 += x2p[t + 128 * i];
        x2g[(size_t)tile * 128 + t] = x2;
        unsigned bits = (unsigned)k1 | ((unsigned)k2 << 10) | ((unsigned)k3 << 20);
        cand[(size_t)tile * 128 + t] =
            make_float4(v1, v2, v3, __int_as_float((int)bits));
    }
}

// --- K3: finish. grid 1024 x 256 thr, t-tile 64, 2 blocks/CU --------------
// reduce cand -> idx/loss (ties -> wave-parallel exact fp64 over top-3),
// gather E rows into LDS, write out0 [B,D,T] + idx.
__global__ __launch_bounds__(256) void finish_kernel(
        const float* __restrict__ X, const float* __restrict__ E,
        const float4* __restrict__ cand, const float* __restrict__ x2g,
        float* __restrict__ out0, float* __restrict__ loss,
        float* __restrict__ idxf_out) {
    extern __shared__ char smem[];
    float* q    = (float*)(smem + SM3_Q);    // [64][257]
    int*   idxs = (int*)(smem + SM3_IDX);
    int*   tiec = (int*)(smem + SM3_TIEC);
    uint2* tiel = (uint2*)(smem + SM3_TIEL);

    int tid = threadIdx.x;
    int lane = tid & 63;
    int w = tid >> 6;                        // 0..3
    int b = blockIdx.x >> 5;                 // 0..31
    int tg0 = (blockIdx.x & 31) << 6;
    size_t n0 = (size_t)blockIdx.x * 64;     // global token base

    if (tid == 0) tiec[0] = 0;
    __syncthreads();

    if (tid < 64) {
        int t = tid;
        float4 c = cand[n0 + t];
        int bits = __float_as_int(c.w);
        int k1 = bits & 1023, k2 = (bits >> 10) & 1023, k3 = (bits >> 20) & 1023;
        float dmin2 = 0.f;
        if (c.x - c.y < THR) {    // near-tie: defer exact fp64 refinement
            int slot = atomicAdd(tiec, 1);
            tiel[slot] = make_uint2(((unsigned)t << 10) | (unsigned)k1,
                                    ((unsigned)k2 << 16) | (unsigned)k3);
        } else {
            idxs[t] = k1;
            idxf_out[(size_t)b * T_SZ + tg0 + t] = (float)k1;
            dmin2 = x2g[n0 + t] - 2.0f * c.x;   // ||x||^2 - 2(x.e - esq/2)
        }
        float lsum = dmin2;
#pragma unroll
        for (int off = 32; off > 0; off >>= 1) lsum += __shfl_down(lsum, off, 64);
        if (tid == 0) atomicAdd(loss, lsum * (0.5f / (float)TOT));
    }
    __syncthreads();

    // wave-parallel exact refinement: one wave per tie, 64 lanes x 4 d each
    {
        int ntie = tiec[0];
        for (int e = w; e < ntie; e += 4) {
            uint2 pk = tiel[e];
            int t = pk.x >> 10;
            int k1 = pk.x & 1023, k2 = pk.y >> 16, k3 = pk.y & 1023;
            const float* e1 = E + (size_t)k1 * D_DIM;
            const float* e2 = E + (size_t)k2 * D_DIM;
            const float* e3 = E + (size_t)k3 * D_DIM;
            const float* xc = X + (size_t)b * ((size_t)D_DIM * T_SZ) + tg0 + t;
            int d0 = lane * 4;
            double d1 = 0.0, d2 = 0.0, d3 = 0.0;
#pragma unroll
            for (int u = 0; u < 4; ++u) {
                int d = d0 + u;
                double xd = (double)xc[(size_t)d * T_SZ];
                double u1 = xd - (double)e1[d];
                double u2 = xd - (double)e2[d];
                double u3 = xd - (double)e3[d];
                d1 += u1 * u1;
                d2 += u2 * u2;
                d3 += u3 * u3;
            }
#pragma unroll
            for (int off = 32; off > 0; off >>= 1) {
                d1 += __shfl_down(d1, off, 64);
                d2 += __shfl_down(d2, off, 64);
                d3 += __shfl_down(d3, off, 64);
            }
            if (lane == 0) {
                int kb = k1; double dm = d1;
                if (d2 < dm || (d2 == dm && k2 < kb)) { kb = k2; dm = d2; }
                if (d3 < dm || (d3 == dm && k3 < kb)) { kb = k3; dm = d3; }
                idxs[t] = kb;
                idxf_out[(size_t)b * T_SZ + tg0 + t] = (float)kb;
                atomicAdd(loss, (float)dm * (0.5f / (float)TOT));
            }
        }
    }
    __syncthreads();

    // gather E rows into q overlay (stride 257 -> conflict-free column reads)
    {
        for (int i = 0; i < 16; ++i) {
            int r = w * 16 + i;
            int row = idxs[r];
            const float* ep = E + (size_t)row * D_DIM;
#pragma unroll
            for (int u = 0; u < 4; ++u)
                q[r * 257 + lane + 64 * u] = ep[lane + 64 * u];
        }
    }
    __syncthreads();

    // write out0 [B,D,T]: lanes over t (coalesced 256B), LDS conflict-free
    {
        int t = tid & 63, dgrp = tid >> 6;
        size_t obase = (size_t)b * ((size_t)D_DIM * T_SZ) + tg0 + t;
#pragma unroll 8
        for (int j = 0; j < 64; ++j) {
            int d = dgrp * 64 + j;
            out0[obase + (size_t)d * T_SZ] = q[t * 257 + d];
        }
    }
}

extern "C" void kernel_launch(void* const* d_in, const int* in_sizes, int n_in,
                              void* d_out, int out_size, void* d_ws, size_t ws_size,
                              hipStream_t stream) {
    const float* X = (const float*)d_in[0];   // [32, 256, 2048] fp32
    const float* E = (const float*)d_in[1];   // [1024, 256] fp32
    float* out = (float*)d_out;
    float* loss = out + LOSS_OFF;
    float* idxf = out + IDX_OFF;

    unsigned short* Ehi = (unsigned short*)((char*)d_ws + WS_EHI);
    float*          x2g = (float*)((char*)d_ws + WS_X2);
    float4*        candp = (float4*)((char*)d_ws + WS_CAND);

    prepack_kernel<<<(32 * NDC * 64 + 255) / 256, 256, 0, stream>>>(E, Ehi, loss);
    argmin_kernel<<<512, 512, SM2_TOT, stream>>>(X, Ehi, candp, x2g);
    finish_kernel<<<1024, 256, SM3_TOT, stream>>>(X, E, candp, x2g, out, loss, idxf);
}

// Round 10
// 374.167 us; speedup vs baseline: 1.8316x; 1.8316x over previous
//
#include <hip/hip_runtime.h>
#include <math.h>

#define K_EMB 1024
#define D_DIM 256
#define T_SZ 2048
#define TOT 16777216        // B*D*T
#define LOSS_OFF 16777216
#define IDX_OFF 16777217
#define NDC 17              // 16 real d-chunks + 1 esq-fold chunk (A-side)
#define THR 0.6f            // ~10 sigma of bf16 score-diff noise -> exact refine

// workspace layout (bytes)
#define WS_ESQ  0           //     4,096  per-code ||e||^2
#define WS_EHI  4096        //   557,056  E frags [32 kc][17 dc][64 lane] x 16B
#define WS_ABL  561152      // 2,097,152  ablation sink [512 blk][1024 thr] f32

// vq_main LDS (bytes); q overlay [0,131584) after main loop
#define SM_XH   0           // 65,536  x frags: [tc4][dc16][64 lane][16B]
#define SM_X2P  65536       //  4,096  per-thread x^2 partials (1024 f32)
#define SM_RV   69632       // 12,288  top3 vals [16w][2tcj][32m][3]
#define SM_RK   81920       // 12,288  top3 keys
#define SM_Q    0           // overlay: 128 rows x 257 f32 = 131,584
#define SM_IDX  131584      //    512  idx per t (above overlay, live to end)
#define SM_TIEC 132096      //      8  tie count
#define SM_TIEL 132104      //  1,024  128 x uint2 tie entries
#define SM_TOT  133128      // -> 1 block/CU, 16 waves (4/SIMD)

typedef __attribute__((ext_vector_type(8)))  __bf16 bf16x8;
typedef __attribute__((ext_vector_type(8)))  short  s16x8;
typedef __attribute__((ext_vector_type(16))) float  f32x16;

__device__ __forceinline__ unsigned short f2bf(float f) {   // RNE fp32->bf16 bits
    unsigned u = __float_as_uint(f);
    u += 0x7FFFu + ((u >> 16) & 1u);
    return (unsigned short)(u >> 16);
}
__device__ __forceinline__ float bf2f(unsigned short h) {
    return __uint_as_float(((unsigned)h) << 16);
}
// BRANCHLESS top-3 insert (value-only; exact ties have gap 0 < THR and are
// resolved by the exact-fp64 refine which applies the smaller-k rule).
// Pure cndmask chain: no divergent control flow, no state shuffling.
__device__ __forceinline__ void ins3(float& v1, int& k1, float& v2, int& k2,
                                     float& v3, int& k3, float v, int k) {
    bool b1 = v > v1, b2 = v > v2, b3 = v > v3;
    v3 = b2 ? v2 : (b3 ? v : v3);
    k3 = b2 ? k2 : (b3 ? k : k3);
    v2 = b1 ? v1 : (b2 ? v : v2);
    k2 = b1 ? k1 : (b2 ? k : k2);
    v1 = b1 ? v : v1;
    k1 = b1 ? k : k1;
}

// --- K0a: per-code squared norms, wave-parallel (R0-proven) ---------------
__global__ __launch_bounds__(256) void esq_kernel(const float* __restrict__ E,
                                                  float* __restrict__ esq,
                                                  float* __restrict__ loss) {
    if (blockIdx.x == 0 && threadIdx.x == 0) loss[0] = 0.f;
    int k = blockIdx.x * 4 + (threadIdx.x >> 6);
    int lane = threadIdx.x & 63;
    const float* er = E + (size_t)k * D_DIM;
    float s = 0.f;
#pragma unroll
    for (int i = 0; i < 4; ++i) { float v = er[lane + 64 * i]; s = fmaf(v, v, s); }
#pragma unroll
    for (int off = 32; off > 0; off >>= 1) s += __shfl_down(s, off, 64);
    if (lane == 0) esq[k] = s;
}

// --- K0b: pre-pack E into MFMA A-frag order (bf16) ------------------------
// frag (kc, dc, lane): A[m=lane&31][kd=(lane>>5)*8+j], k=kc*32+m,
// d=dc*16+(lane>>5)*8+j. dc==16 = esq-fold: slot0=bf16(-esq/2), slot1=residual.
__global__ __launch_bounds__(256) void prepack_kernel(const float* __restrict__ E,
        const float* __restrict__ esq, unsigned short* __restrict__ Ehi) {
    int gid = blockIdx.x * 256 + threadIdx.x;        // == (kc*17+dc)*64 + lane
    if (gid >= 32 * NDC * 64) return;
    int lane = gid & 63;
    int dc = (gid >> 6) % NDC;
    int kc = gid / (NDC * 64);
    int m = lane & 31, dh = lane >> 5;
    int k = kc * 32 + m;
    unsigned short h8[8];
#pragma unroll
    for (int j = 0; j < 8; ++j) h8[j] = 0;
    if (dc < 16) {
        int d0 = dc * 16 + dh * 8;
        const float* ep = E + (size_t)k * D_DIM + d0;
#pragma unroll
        for (int j = 0; j < 8; ++j) h8[j] = f2bf(ep[j]);
    } else if (dh == 0) {
        float v = -0.5f * esq[k];
        unsigned short h = f2bf(v);
        h8[0] = h;
        h8[1] = f2bf(v - bf2f(h));
    }
    s16x8 hv;
#pragma unroll
    for (int j = 0; j < 8; ++j) hv[j] = (short)h8[j];
    ((s16x8*)Ehi)[gid] = hv;
}

// --- K1: fused main. grid 512, 1024 thr / 16 waves (4/SIMD) ---------------
// R2-proven 16-wave shape (135us/round there WITH 3x today's MFMA work):
// wave w = (kq = w>>1, tc-pair tcb = (w&1)*2). Per rnd (4): kc = rnd*8+kq,
// acc[2 tcj] f32x16 = 32 AGPR; ~85 total regs (fits the compiler's 128
// budget, no spill pressure). Epilogue fused back in (R0-proven code):
// the split finish_kernel cost ~225us standalone vs ~60us fused.
__global__ __launch_bounds__(1024) void vq_main_kernel(
        const float* __restrict__ X, const unsigned short* __restrict__ Ehi,
        const float* __restrict__ E, float* __restrict__ out0,
        float* __restrict__ loss, float* __restrict__ idxf_out) {
    extern __shared__ char smem[];
    unsigned short* xhf = (unsigned short*)(smem + SM_XH);
    float* x2p = (float*)(smem + SM_X2P);
    float* redv = (float*)(smem + SM_RV);
    int*   redk = (int*)(smem + SM_RK);
    float* q    = (float*)(smem + SM_Q);     // overlay after main loop
    int*   idxs = (int*)(smem + SM_IDX);
    int*   tiec = (int*)(smem + SM_TIEC);
    uint2* tiel = (uint2*)(smem + SM_TIEL);

    int tid = threadIdx.x;
    int lane = tid & 63;
    int w = tid >> 6;                        // 0..15
    int dhalf = lane >> 5;
    int b = blockIdx.x >> 4;                 // 16 tiles of 128 t per b
    int tg0 = (blockIdx.x & 15) << 7;

    if (tid == 0) tiec[0] = 0;

    // ---- stage X tile [128 t][256 d] -> frag-order bf16 + ||x||^2 ----
    {
        int t = tid & 127, dblk = tid >> 7;  // 8 dblk x 32 d
        int tc = t >> 5, m = t & 31;
        const float* xp = X + (size_t)b * ((size_t)D_DIM * T_SZ) + tg0 + t;
        float x2a = 0.f;
#pragma unroll
        for (int g = 0; g < 4; ++g) {
            int d0 = dblk * 32 + g * 8;
            s16x8 hv;
#pragma unroll
            for (int j = 0; j < 8; ++j) {
                float xv = xp[(size_t)(d0 + j) * T_SZ];
                hv[j] = (short)f2bf(xv);
                x2a = fmaf(xv, xv, x2a);
            }
            int fi = (tc * 16 + (d0 >> 4)) * 64 + ((d0 >> 3) & 1) * 32 + m;
            ((s16x8*)xhf)[fi] = hv;
        }
        x2p[tid] = x2a;
    }
    __syncthreads();

    const s16x8* ehp = (const s16x8*)Ehi;
    const s16x8* bhf = (const s16x8*)xhf;
    int kq = w >> 1;                         // 0..7
    int tcb = (w & 1) * 2;                   // tc pair {tcb, tcb+1}

    s16x8 bfold = {0, 0, 0, 0, 0, 0, 0, 0};
    if (dhalf == 0) { bfold[0] = (short)0x3F80; bfold[1] = (short)0x3F80; }
    bf16x8 bh_fold = __builtin_bit_cast(bf16x8, bfold);

    float v1s[2], v2s[2], v3s[2];
    int k1s[2], k2s[2], k3s[2];
#pragma unroll
    for (int j = 0; j < 2; ++j) { v1s[j] = -INFINITY; v2s[j] = -INFINITY;
                                  v3s[j] = -INFINITY; k1s[j] = 0; k2s[j] = 0;
                                  k3s[j] = 0; }

#pragma unroll 1
    for (int rnd = 0; rnd < 4; ++rnd) {
        int kc = rnd * 8 + kq;
        f32x16 acc0, acc1;
#pragma unroll
        for (int i = 0; i < 16; ++i) { acc0[i] = 0.f; acc1[i] = 0.f; }

        size_t ab = (size_t)kc * NDC * 64 + lane;
        s16x8 nh = ehp[ab];                  // depth-1 rotating E prefetch

#pragma unroll 1
        for (int dc = 0; dc < 16; ++dc) {
            bf16x8 ah = __builtin_bit_cast(bf16x8, nh);
            nh = ehp[ab + (size_t)(dc + 1) * 64];    // dc==15 -> fold chunk
            bf16x8 bh0 = __builtin_bit_cast(bf16x8, bhf[(tcb * 16 + dc) * 64 + lane]);
            bf16x8 bh1 = __builtin_bit_cast(bf16x8, bhf[((tcb + 1) * 16 + dc) * 64 + lane]);
            acc0 = __builtin_amdgcn_mfma_f32_32x32x16_bf16(ah, bh0, acc0, 0, 0, 0);
            acc1 = __builtin_amdgcn_mfma_f32_32x32x16_bf16(ah, bh1, acc1, 0, 0, 0);
        }
        {   // esq-fold chunk (dc==16, in nh): B constant 1.0 in kd slots 0,1
            bf16x8 ah = __builtin_bit_cast(bf16x8, nh);
            acc0 = __builtin_amdgcn_mfma_f32_32x32x16_bf16(ah, bh_fold, acc0, 0, 0, 0);
            acc1 = __builtin_amdgcn_mfma_f32_32x32x16_bf16(ah, bh_fold, acc1, 0, 0, 0);
        }
        // scan acc -> running top3 (branchless)
        int kb = kc * 32 + 4 * dhalf;
#pragma unroll
        for (int ri = 0; ri < 16; ++ri) {
            int kk = kb + (ri & 3) + 8 * (ri >> 2);
            ins3(v1s[0], k1s[0], v2s[0], k2s[0], v3s[0], k3s[0], acc0[ri], kk);
            ins3(v1s[1], k1s[1], v2s[1], k2s[1], v3s[1], k3s[1], acc1[ri], kk);
        }
    }

    // merge lane^32 partner (same t, complementary k rows), store to LDS
#pragma unroll
    for (int tcj = 0; tcj < 2; ++tcj) {
        float pv1 = __shfl_xor(v1s[tcj], 32, 64); int pk1 = __shfl_xor(k1s[tcj], 32, 64);
        float pv2 = __shfl_xor(v2s[tcj], 32, 64); int pk2 = __shfl_xor(k2s[tcj], 32, 64);
        float pv3 = __shfl_xor(v3s[tcj], 32, 64); int pk3 = __shfl_xor(k3s[tcj], 32, 64);
        ins3(v1s[tcj], k1s[tcj], v2s[tcj], k2s[tcj], v3s[tcj], k3s[tcj], pv1, pk1);
        ins3(v1s[tcj], k1s[tcj], v2s[tcj], k2s[tcj], v3s[tcj], k3s[tcj], pv2, pk2);
        ins3(v1s[tcj], k1s[tcj], v2s[tcj], k2s[tcj], v3s[tcj], k3s[tcj], pv3, pk3);
        if (dhalf == 0) {
            int base = ((w * 2 + tcj) * 32 + (lane & 31)) * 3;
            redv[base]     = v1s[tcj]; redk[base]     = k1s[tcj];
            redv[base + 1] = v2s[tcj]; redk[base + 1] = k2s[tcj];
            redv[base + 2] = v3s[tcj]; redk[base + 2] = k3s[tcj];
        }
    }
    __syncthreads();

    // per-t reduce across the 8 contributing waves; near-ties deferred
    if (tid < 128) {
        int t = tid, tc = t >> 5, m = t & 31;
        int p = tc >> 1, tcj = tc & 1;       // wave parity / tcj for this tc
        float v1 = -INFINITY, v2 = -INFINITY, v3 = -INFINITY;
        int k1 = 0, k2 = 0, k3 = 0;
#pragma unroll
        for (int qq = 0; qq < 8; ++qq) {
            int ww = qq * 2 + p;
            int base = ((ww * 2 + tcj) * 32 + m) * 3;
            ins3(v1, k1, v2, k2, v3, k3, redv[base], redk[base]);
            ins3(v1, k1, v2, k2, v3, k3, redv[base + 1], redk[base + 1]);
            ins3(v1, k1, v2, k2, v3, k3, redv[base + 2], redk[base + 2]);
        }
        float dmin2 = 0.f;
        if (v1 - v2 < THR) {      // near-tie: defer exact fp64 refinement
            int slot = atomicAdd(tiec, 1);
            tiel[slot] = make_uint2(((unsigned)t << 10) | (unsigned)k1,
                                    ((unsigned)k2 << 16) | (unsigned)k3);
        } else {
            idxs[t] = k1;
            idxf_out[(size_t)b * T_SZ + tg0 + t] = (float)k1;
            float x2 = 0.f;
#pragma unroll
            for (int i = 0; i < 8; ++i) x2 += x2p[t + 128 * i];
            dmin2 = x2 - 2.0f * v1;   // ||x||^2 - 2(x.e - esq/2) = ||x-e||^2
        }
        float lsum = dmin2;
#pragma unroll
        for (int off = 32; off > 0; off >>= 1) lsum += __shfl_down(lsum, off, 64);
        if ((tid & 63) == 0) atomicAdd(loss, lsum * (0.5f / (float)TOT));
    }
    __syncthreads();

    // wave-parallel exact refinement: one wave per tie, 64 lanes x 4 d each
    {
        int ntie = tiec[0];
        for (int e = w; e < ntie; e += 16) {
            uint2 pk = tiel[e];
            int t = pk.x >> 10;
            int k1 = pk.x & 1023, k2 = pk.y >> 16, k3 = pk.y & 1023;
            const float* e1 = E + (size_t)k1 * D_DIM;
            const float* e2 = E + (size_t)k2 * D_DIM;
            const float* e3 = E + (size_t)k3 * D_DIM;
            const float* xc = X + (size_t)b * ((size_t)D_DIM * T_SZ) + tg0 + t;
            int d0 = lane * 4;
            double d1 = 0.0, d2 = 0.0, d3 = 0.0;
#pragma unroll
            for (int u = 0; u < 4; ++u) {
                int d = d0 + u;
                double xd = (double)xc[(size_t)d * T_SZ];
                double u1 = xd - (double)e1[d];
                double u2 = xd - (double)e2[d];
                double u3 = xd - (double)e3[d];
                d1 += u1 * u1;
                d2 += u2 * u2;
                d3 += u3 * u3;
            }
#pragma unroll
            for (int off = 32; off > 0; off >>= 1) {
                d1 += __shfl_down(d1, off, 64);
                d2 += __shfl_down(d2, off, 64);
                d3 += __shfl_down(d3, off, 64);
            }
            if (lane == 0) {
                int kb = k1; double dm = d1;
                if (d2 < dm || (d2 == dm && k2 < kb)) { kb = k2; dm = d2; }
                if (d3 < dm || (d3 == dm && k3 < kb)) { kb = k3; dm = d3; }
                idxs[t] = kb;
                idxf_out[(size_t)b * T_SZ + tg0 + t] = (float)kb;
                atomicAdd(loss, (float)dm * (0.5f / (float)TOT));
            }
        }
    }
    __syncthreads();

    // gather E rows into q overlay (stride 257 -> conflict-free column reads)
    {
        for (int i = 0; i < 8; ++i) {
            int r = w * 8 + i;
            int row = idxs[r];
            const float* ep = E + (size_t)row * D_DIM;
#pragma unroll
            for (int u = 0; u < 4; ++u)
                q[r * 257 + lane + 64 * u] = ep[lane + 64 * u];
        }
    }
    __syncthreads();

    // write out0 [B,D,T]: lanes over t (coalesced 256B), LDS conflict-free
    {
        int t = tid & 127, dgrp = tid >> 7;
        size_t obase = (size_t)b * ((size_t)D_DIM * T_SZ) + tg0 + t;
#pragma unroll 8
        for (int j = 0; j < 32; ++j) {
            int d = dgrp * 32 + j;
            out0[obase + (size_t)d * T_SZ] = q[t * 257 + d];
        }
    }
}

// --- K2 (INSTRUMENT): main-loop-only ablation twin ------------------------
// Identical staging + 4-rnd MFMA/E loop; scan/merge/epilogue DELETED. acc
// kept live via element-0 sum -> global sink (prevents DCE of the MFMA/E
// chain). Its dur = total - others => prices the scan+epilogue removal.
__global__ __launch_bounds__(1024) void vq_abl_kernel(
        const float* __restrict__ X, const unsigned short* __restrict__ Ehi,
        float* __restrict__ abl) {
    extern __shared__ char smem[];
    unsigned short* xhf = (unsigned short*)(smem + SM_XH);
    float* x2p = (float*)(smem + SM_X2P);

    int tid = threadIdx.x;
    int lane = tid & 63;
    int w = tid >> 6;
    int dhalf = lane >> 5;
    int b = blockIdx.x >> 4;
    int tg0 = (blockIdx.x & 15) << 7;

    {
        int t = tid & 127, dblk = tid >> 7;
        int tc = t >> 5, m = t & 31;
        const float* xp = X + (size_t)b * ((size_t)D_DIM * T_SZ) + tg0 + t;
        float x2a = 0.f;
#pragma unroll
        for (int g = 0; g < 4; ++g) {
            int d0 = dblk * 32 + g * 8;
            s16x8 hv;
#pragma unroll
            for (int j = 0; j < 8; ++j) {
                float xv = xp[(size_t)(d0 + j) * T_SZ];
                hv[j] = (short)f2bf(xv);
                x2a = fmaf(xv, xv, x2a);
            }
            int fi = (tc * 16 + (d0 >> 4)) * 64 + ((d0 >> 3) & 1) * 32 + m;
            ((s16x8*)xhf)[fi] = hv;
        }
        x2p[tid] = x2a;
    }
    __syncthreads();

    const s16x8* ehp = (const s16x8*)Ehi;
    const s16x8* bhf = (const s16x8*)xhf;
    int kq = w >> 1;
    int tcb = (w & 1) * 2;

    s16x8 bfold = {0, 0, 0, 0, 0, 0, 0, 0};
    if (dhalf == 0) { bfold[0] = (short)0x3F80; bfold[1] = (short)0x3F80; }
    bf16x8 bh_fold = __builtin_bit_cast(bf16x8, bfold);

    float ksum = 0.f;
#pragma unroll 1
    for (int rnd = 0; rnd < 4; ++rnd) {
        int kc = rnd * 8 + kq;
        f32x16 acc0, acc1;
#pragma unroll
        for (int i = 0; i < 16; ++i) { acc0[i] = 0.f; acc1[i] = 0.f; }
        size_t ab = (size_t)kc * NDC * 64 + lane;
        s16x8 nh = ehp[ab];
#pragma unroll 1
        for (int dc = 0; dc < 16; ++dc) {
            bf16x8 ah = __builtin_bit_cast(bf16x8, nh);
            nh = ehp[ab + (size_t)(dc + 1) * 64];
            bf16x8 bh0 = __builtin_bit_cast(bf16x8, bhf[(tcb * 16 + dc) * 64 + lane]);
            bf16x8 bh1 = __builtin_bit_cast(bf16x8, bhf[((tcb + 1) * 16 + dc) * 64 + lane]);
            acc0 = __builtin_amdgcn_mfma_f32_32x32x16_bf16(ah, bh0, acc0, 0, 0, 0);
            acc1 = __builtin_amdgcn_mfma_f32_32x32x16_bf16(ah, bh1, acc1, 0, 0, 0);
        }
        {
            bf16x8 ah = __builtin_bit_cast(bf16x8, nh);
            acc0 = __builtin_amdgcn_mfma_f32_32x32x16_bf16(ah, bh_fold, acc0, 0, 0, 0);
            acc1 = __builtin_amdgcn_mfma_f32_32x32x16_bf16(ah, bh_fold, acc1, 0, 0, 0);
        }
        ksum += acc0[0] + acc1[0];           // keep-alive, ~free
    }
    abl[(size_t)blockIdx.x * 1024 + tid] = ksum;
}

extern "C" void kernel_launch(void* const* d_in, const int* in_sizes, int n_in,
                              void* d_out, int out_size, void* d_ws, size_t ws_size,
                              hipStream_t stream) {
    const float* X = (const float*)d_in[0];   // [32, 256, 2048] fp32
    const float* E = (const float*)d_in[1];   // [1024, 256] fp32
    float* out = (float*)d_out;
    float* loss = out + LOSS_OFF;
    float* idxf = out + IDX_OFF;

    float*          esq = (float*)((char*)d_ws + WS_ESQ);
    unsigned short* Ehi = (unsigned short*)((char*)d_ws + WS_EHI);
    float*          abl = (float*)((char*)d_ws + WS_ABL);

    esq_kernel<<<K_EMB / 4, 256, 0, stream>>>(E, esq, loss);
    prepack_kernel<<<(32 * NDC * 64 + 255) / 256, 256, 0, stream>>>(E, esq, Ehi);
    vq_main_kernel<<<512, 1024, SM_TOT, stream>>>(X, Ehi, E, out, loss, idxf);
    vq_abl_kernel<<<512, 1024, SM_TOT, stream>>>(X, Ehi, abl);
}

// Round 11
// 313.457 us; speedup vs baseline: 2.1863x; 1.1937x over previous
//
#include <hip/hip_runtime.h>
#include <math.h>

#define K_EMB 1024
#define D_DIM 256
#define T_SZ 2048
#define TOT 16777216        // B*D*T
#define LOSS_OFF 16777216
#define IDX_OFF 16777217
#define NDC 17              // 16 real d-chunks + 1 esq-fold chunk (A-side)
#define THR 0.6f            // ~16 sigma of bf16 score-diff noise -> exact refine

// workspace layout (bytes)
#define WS_ESQ  0           //     4,096  per-code ||e||^2
#define WS_EHI  4096        //   557,056  E frags [32 kc][17 dc][64 lane] x 16B

// vq_main LDS (bytes); q overlay [0,131584) after main loop
#define SM_XH   0           // 65,536  x frags: [tc4][dc16][64 lane][16B]
#define SM_X2P  65536       //  4,096  per-thread x^2 partials (1024 f32)
#define SM_RV   69632       // 12,288  top3 vals [16w][2tcj][32m][3]
#define SM_RK   81920       // 12,288  top3 keys
#define SM_Q    0           // overlay: 128 rows x 257 f32 = 131,584
#define SM_IDX  131584      //    512  idx per t (above overlay, live to end)
#define SM_TIEC 132096      //      8  tie count
#define SM_TIEL 132104      //  1,024  128 x uint2 tie entries
#define SM_TOT  133128      // -> 1 block/CU, 16 waves (4/SIMD)

typedef __attribute__((ext_vector_type(8)))  __bf16 bf16x8;
typedef __attribute__((ext_vector_type(8)))  short  s16x8;
typedef __attribute__((ext_vector_type(16))) float  f32x16;

__device__ __forceinline__ unsigned short f2bf(float f) {   // RNE fp32->bf16 bits
    unsigned u = __float_as_uint(f);
    u += 0x7FFFu + ((u >> 16) & 1u);
    return (unsigned short)(u >> 16);
}
__device__ __forceinline__ float bf2f(unsigned short h) {
    return __uint_as_float(((unsigned)h) << 16);
}
// BRANCHLESS top-3 insert (value-only; exact ties have gap 0 < THR and are
// resolved by the exact-fp64 refine which applies the smaller-k rule).
__device__ __forceinline__ void ins3(float& v1, int& k1, float& v2, int& k2,
                                     float& v3, int& k3, float v, int k) {
    bool b1 = v > v1, b2 = v > v2, b3 = v > v3;
    v3 = b2 ? v2 : (b3 ? v : v3);
    k3 = b2 ? k2 : (b3 ? k : k3);
    v2 = b1 ? v1 : (b2 ? v : v2);
    k2 = b1 ? k1 : (b2 ? k : k2);
    v1 = b1 ? v : v1;
    k1 = b1 ? k : k1;
}

// --- K0a: per-code squared norms, wave-parallel ---------------------------
__global__ __launch_bounds__(256) void esq_kernel(const float* __restrict__ E,
                                                  float* __restrict__ esq,
                                                  float* __restrict__ loss) {
    if (blockIdx.x == 0 && threadIdx.x == 0) loss[0] = 0.f;
    int k = blockIdx.x * 4 + (threadIdx.x >> 6);
    int lane = threadIdx.x & 63;
    const float* er = E + (size_t)k * D_DIM;
    float s = 0.f;
#pragma unroll
    for (int i = 0; i < 4; ++i) { float v = er[lane + 64 * i]; s = fmaf(v, v, s); }
#pragma unroll
    for (int off = 32; off > 0; off >>= 1) s += __shfl_down(s, off, 64);
    if (lane == 0) esq[k] = s;
}

// --- K0b: pre-pack E into MFMA A-frag order (bf16) ------------------------
// frag (kc, dc, lane): A[m=lane&31][kd=(lane>>5)*8+j], k=kc*32+m,
// d=dc*16+(lane>>5)*8+j. dc==16 = esq-fold: slot0=bf16(-esq/2), slot1=residual.
__global__ __launch_bounds__(256) void prepack_kernel(const float* __restrict__ E,
        const float* __restrict__ esq, unsigned short* __restrict__ Ehi) {
    int gid = blockIdx.x * 256 + threadIdx.x;        // == (kc*17+dc)*64 + lane
    if (gid >= 32 * NDC * 64) return;
    int lane = gid & 63;
    int dc = (gid >> 6) % NDC;
    int kc = gid / (NDC * 64);
    int m = lane & 31, dh = lane >> 5;
    int k = kc * 32 + m;
    unsigned short h8[8];
#pragma unroll
    for (int j = 0; j < 8; ++j) h8[j] = 0;
    if (dc < 16) {
        int d0 = dc * 16 + dh * 8;
        const float* ep = E + (size_t)k * D_DIM + d0;
#pragma unroll
        for (int j = 0; j < 8; ++j) h8[j] = f2bf(ep[j]);
    } else if (dh == 0) {
        float v = -0.5f * esq[k];
        unsigned short h = f2bf(v);
        h8[0] = h;
        h8[1] = f2bf(v - bf2f(h));
    }
    s16x8 hv;
#pragma unroll
    for (int j = 0; j < 8; ++j) hv[j] = (short)h8[j];
    ((s16x8*)Ehi)[gid] = hv;
}

// --- K1: fused main. grid 512, 1024 thr / 16 waves (4/SIMD) ---------------
// L2-THRASH FIX (the R10 ablation's finding): the main loop re-reads E-frags
// ~271 MB/round chip-wide, designed as L2 hits (E=544KB per 4MB XCD-L2) —
// but X-staging (4.2 MB/XCD/round) + out0 stores (4.2 MB/XCD/round) were
// wiping L2 every round, demoting E-reads to L3 (~130us, = the vq_abl cost).
// Fix: X-staging loads and out0 stores are NON-TEMPORAL (evict-first), so
// E stays L2-resident. Everything else identical to the verified R10 kernel.
__global__ __launch_bounds__(1024) void vq_main_kernel(
        const float* __restrict__ X, const unsigned short* __restrict__ Ehi,
        const float* __restrict__ E, float* __restrict__ out0,
        float* __restrict__ loss, float* __restrict__ idxf_out) {
    extern __shared__ char smem[];
    unsigned short* xhf = (unsigned short*)(smem + SM_XH);
    float* x2p = (float*)(smem + SM_X2P);
    float* redv = (float*)(smem + SM_RV);
    int*   redk = (int*)(smem + SM_RK);
    float* q    = (float*)(smem + SM_Q);     // overlay after main loop
    int*   idxs = (int*)(smem + SM_IDX);
    int*   tiec = (int*)(smem + SM_TIEC);
    uint2* tiel = (uint2*)(smem + SM_TIEL);

    int tid = threadIdx.x;
    int lane = tid & 63;
    int w = tid >> 6;                        // 0..15
    int dhalf = lane >> 5;
    int b = blockIdx.x >> 4;                 // 16 tiles of 128 t per b
    int tg0 = (blockIdx.x & 15) << 7;

    if (tid == 0) tiec[0] = 0;

    // ---- stage X tile [128 t][256 d] -> frag-order bf16 + ||x||^2 ----
    // NT loads: X is touched once; keep it out of L2 so E-frags stay hot.
    {
        int t = tid & 127, dblk = tid >> 7;  // 8 dblk x 32 d
        int tc = t >> 5, m = t & 31;
        const float* xp = X + (size_t)b * ((size_t)D_DIM * T_SZ) + tg0 + t;
        float x2a = 0.f;
#pragma unroll
        for (int g = 0; g < 4; ++g) {
            int d0 = dblk * 32 + g * 8;
            s16x8 hv;
#pragma unroll
            for (int j = 0; j < 8; ++j) {
                float xv = __builtin_nontemporal_load(
                               &xp[(size_t)(d0 + j) * T_SZ]);
                hv[j] = (short)f2bf(xv);
                x2a = fmaf(xv, xv, x2a);
            }
            int fi = (tc * 16 + (d0 >> 4)) * 64 + ((d0 >> 3) & 1) * 32 + m;
            ((s16x8*)xhf)[fi] = hv;
        }
        x2p[tid] = x2a;
    }
    __syncthreads();

    const s16x8* ehp = (const s16x8*)Ehi;
    const s16x8* bhf = (const s16x8*)xhf;
    int kq = w >> 1;                         // 0..7
    int tcb = (w & 1) * 2;                   // tc pair {tcb, tcb+1}

    s16x8 bfold = {0, 0, 0, 0, 0, 0, 0, 0};
    if (dhalf == 0) { bfold[0] = (short)0x3F80; bfold[1] = (short)0x3F80; }
    bf16x8 bh_fold = __builtin_bit_cast(bf16x8, bfold);

    float v1s[2], v2s[2], v3s[2];
    int k1s[2], k2s[2], k3s[2];
#pragma unroll
    for (int j = 0; j < 2; ++j) { v1s[j] = -INFINITY; v2s[j] = -INFINITY;
                                  v3s[j] = -INFINITY; k1s[j] = 0; k2s[j] = 0;
                                  k3s[j] = 0; }

#pragma unroll 1
    for (int rnd = 0; rnd < 4; ++rnd) {
        int kc = rnd * 8 + kq;
        f32x16 acc0, acc1;
#pragma unroll
        for (int i = 0; i < 16; ++i) { acc0[i] = 0.f; acc1[i] = 0.f; }

        size_t ab = (size_t)kc * NDC * 64 + lane;
        s16x8 nh = ehp[ab];                  // depth-1 rotating E prefetch

#pragma unroll 1
        for (int dc = 0; dc < 16; ++dc) {
            bf16x8 ah = __builtin_bit_cast(bf16x8, nh);
            nh = ehp[ab + (size_t)(dc + 1) * 64];    // dc==15 -> fold chunk
            bf16x8 bh0 = __builtin_bit_cast(bf16x8, bhf[(tcb * 16 + dc) * 64 + lane]);
            bf16x8 bh1 = __builtin_bit_cast(bf16x8, bhf[((tcb + 1) * 16 + dc) * 64 + lane]);
            acc0 = __builtin_amdgcn_mfma_f32_32x32x16_bf16(ah, bh0, acc0, 0, 0, 0);
            acc1 = __builtin_amdgcn_mfma_f32_32x32x16_bf16(ah, bh1, acc1, 0, 0, 0);
        }
        {   // esq-fold chunk (dc==16, in nh): B constant 1.0 in kd slots 0,1
            bf16x8 ah = __builtin_bit_cast(bf16x8, nh);
            acc0 = __builtin_amdgcn_mfma_f32_32x32x16_bf16(ah, bh_fold, acc0, 0, 0, 0);
            acc1 = __builtin_amdgcn_mfma_f32_32x32x16_bf16(ah, bh_fold, acc1, 0, 0, 0);
        }
        // scan acc -> running top3 (branchless)
        int kb = kc * 32 + 4 * dhalf;
#pragma unroll
        for (int ri = 0; ri < 16; ++ri) {
            int kk = kb + (ri & 3) + 8 * (ri >> 2);
            ins3(v1s[0], k1s[0], v2s[0], k2s[0], v3s[0], k3s[0], acc0[ri], kk);
            ins3(v1s[1], k1s[1], v2s[1], k2s[1], v3s[1], k3s[1], acc1[ri], kk);
        }
    }

    // merge lane^32 partner (same t, complementary k rows), store to LDS
#pragma unroll
    for (int tcj = 0; tcj < 2; ++tcj) {
        float pv1 = __shfl_xor(v1s[tcj], 32, 64); int pk1 = __shfl_xor(k1s[tcj], 32, 64);
        float pv2 = __shfl_xor(v2s[tcj], 32, 64); int pk2 = __shfl_xor(k2s[tcj], 32, 64);
        float pv3 = __shfl_xor(v3s[tcj], 32, 64); int pk3 = __shfl_xor(k3s[tcj], 32, 64);
        ins3(v1s[tcj], k1s[tcj], v2s[tcj], k2s[tcj], v3s[tcj], k3s[tcj], pv1, pk1);
        ins3(v1s[tcj], k1s[tcj], v2s[tcj], k2s[tcj], v3s[tcj], k3s[tcj], pv2, pk2);
        ins3(v1s[tcj], k1s[tcj], v2s[tcj], k2s[tcj], v3s[tcj], k3s[tcj], pv3, pk3);
        if (dhalf == 0) {
            int base = ((w * 2 + tcj) * 32 + (lane & 31)) * 3;
            redv[base]     = v1s[tcj]; redk[base]     = k1s[tcj];
            redv[base + 1] = v2s[tcj]; redk[base + 1] = k2s[tcj];
            redv[base + 2] = v3s[tcj]; redk[base + 2] = k3s[tcj];
        }
    }
    __syncthreads();

    // per-t reduce across the 8 contributing waves; near-ties deferred
    if (tid < 128) {
        int t = tid, tc = t >> 5, m = t & 31;
        int p = tc >> 1, tcj = tc & 1;       // wave parity / tcj for this tc
        float v1 = -INFINITY, v2 = -INFINITY, v3 = -INFINITY;
        int k1 = 0, k2 = 0, k3 = 0;
#pragma unroll
        for (int qq = 0; qq < 8; ++qq) {
            int ww = qq * 2 + p;
            int base = ((ww * 2 + tcj) * 32 + m) * 3;
            ins3(v1, k1, v2, k2, v3, k3, redv[base], redk[base]);
            ins3(v1, k1, v2, k2, v3, k3, redv[base + 1], redk[base + 1]);
            ins3(v1, k1, v2, k2, v3, k3, redv[base + 2], redk[base + 2]);
        }
        float dmin2 = 0.f;
        if (v1 - v2 < THR) {      // near-tie: defer exact fp64 refinement
            int slot = atomicAdd(tiec, 1);
            tiel[slot] = make_uint2(((unsigned)t << 10) | (unsigned)k1,
                                    ((unsigned)k2 << 16) | (unsigned)k3);
        } else {
            idxs[t] = k1;
            idxf_out[(size_t)b * T_SZ + tg0 + t] = (float)k1;
            float x2 = 0.f;
#pragma unroll
            for (int i = 0; i < 8; ++i) x2 += x2p[t + 128 * i];
            dmin2 = x2 - 2.0f * v1;   // ||x||^2 - 2(x.e - esq/2) = ||x-e||^2
        }
        float lsum = dmin2;
#pragma unroll
        for (int off = 32; off > 0; off >>= 1) lsum += __shfl_down(lsum, off, 64);
        if ((tid & 63) == 0) atomicAdd(loss, lsum * (0.5f / (float)TOT));
    }
    __syncthreads();

    // wave-parallel exact refinement: one wave per tie, 64 lanes x 4 d each
    // (measured ~1-2 ties/block at THR=0.6; X re-reads are small)
    {
        int ntie = tiec[0];
        for (int e = w; e < ntie; e += 16) {
            uint2 pk = tiel[e];
            int t = pk.x >> 10;
            int k1 = pk.x & 1023, k2 = pk.y >> 16, k3 = pk.y & 1023;
            const float* e1 = E + (size_t)k1 * D_DIM;
            const float* e2 = E + (size_t)k2 * D_DIM;
            const float* e3 = E + (size_t)k3 * D_DIM;
            const float* xc = X + (size_t)b * ((size_t)D_DIM * T_SZ) + tg0 + t;
            int d0 = lane * 4;
            double d1 = 0.0, d2 = 0.0, d3 = 0.0;
#pragma unroll
            for (int u = 0; u < 4; ++u) {
                int d = d0 + u;
                double xd = (double)xc[(size_t)d * T_SZ];
                double u1 = xd - (double)e1[d];
                double u2 = xd - (double)e2[d];
                double u3 = xd - (double)e3[d];
                d1 += u1 * u1;
                d2 += u2 * u2;
                d3 += u3 * u3;
            }
#pragma unroll
            for (int off = 32; off > 0; off >>= 1) {
                d1 += __shfl_down(d1, off, 64);
                d2 += __shfl_down(d2, off, 64);
                d3 += __shfl_down(d3, off, 64);
            }
            if (lane == 0) {
                int kb = k1; double dm = d1;
                if (d2 < dm || (d2 == dm && k2 < kb)) { kb = k2; dm = d2; }
                if (d3 < dm || (d3 == dm && k3 < kb)) { kb = k3; dm = d3; }
                idxs[t] = kb;
                idxf_out[(size_t)b * T_SZ + tg0 + t] = (float)kb;
                atomicAdd(loss, (float)dm * (0.5f / (float)TOT));
            }
        }
    }
    __syncthreads();

    // gather E rows into q overlay (stride 257 -> conflict-free column reads)
    {
        for (int i = 0; i < 8; ++i) {
            int r = w * 8 + i;
            int row = idxs[r];
            const float* ep = E + (size_t)row * D_DIM;
#pragma unroll
            for (int u = 0; u < 4; ++u)
                q[r * 257 + lane + 64 * u] = ep[lane + 64 * u];
        }
    }
    __syncthreads();

    // write out0 [B,D,T]: NT stores (streaming, never re-read -> keep out of
    // L2); lanes over t (coalesced 256B), LDS reads conflict-free
    {
        int t = tid & 127, dgrp = tid >> 7;
        size_t obase = (size_t)b * ((size_t)D_DIM * T_SZ) + tg0 + t;
#pragma unroll 8
        for (int j = 0; j < 32; ++j) {
            int d = dgrp * 32 + j;
            __builtin_nontemporal_store(q[t * 257 + d],
                                        &out0[obase + (size_t)d * T_SZ]);
        }
    }
}

extern "C" void kernel_launch(void* const* d_in, const int* in_sizes, int n_in,
                              void* d_out, int out_size, void* d_ws, size_t ws_size,
                              hipStream_t stream) {
    const float* X = (const float*)d_in[0];   // [32, 256, 2048] fp32
    const float* E = (const float*)d_in[1];   // [1024, 256] fp32
    float* out = (float*)d_out;
    float* loss = out + LOSS_OFF;
    float* idxf = out + IDX_OFF;

    float*          esq = (float*)((char*)d_ws + WS_ESQ);
    unsigned short* Ehi = (unsigned short*)((char*)d_ws + WS_EHI);

    esq_kernel<<<K_EMB / 4, 256, 0, stream>>>(E, esq, loss);
    prepack_kernel<<<(32 * NDC * 64 + 255) / 256, 256, 0, stream>>>(E, esq, Ehi);
    vq_main_kernel<<<512, 1024, SM_TOT, stream>>>(X, Ehi, E, out, loss, idxf);
}

// Round 12
// 195.399 us; speedup vs baseline: 3.5072x; 1.6042x over previous
//
#include <hip/hip_runtime.h>
#include <math.h>

#define K_EMB 1024
#define D_DIM 256
#define T_SZ 2048
#define TOT 16777216        // B*D*T
#define LOSS_OFF 16777216
#define IDX_OFF 16777217
#define NDC 17              // 16 real d-chunks + 1 esq-fold chunk (A-side)
#define THR 0.6f            // ~10 sigma of bf16 score-diff noise -> exact refine

// workspace layout (bytes)
#define WS_ESQ  0           //     4,096  per-code ||e||^2
#define WS_EHI  4096        //   557,056  E frags [32 kc][17 dc][64 lane] x 16B

// vq_main LDS (bytes); q overlay [0,131584) after main loop
#define SM_XH   0           // 65,536  x frags: [tc4][dc16][64 lane][16B]
#define SM_X2P  65536       //  4,096  per-thread x^2 partials (1024 f32)
#define SM_RV   69632       // 12,288  top3 vals [16w][2tcj][32m][3]
#define SM_RK   81920       // 12,288  top3 keys
#define SM_Q    0           // overlay: 128 rows x 257 f32 = 131,584
#define SM_IDX  131584      //    512  idx per t (above overlay, live to end)
#define SM_TIEC 132096      //      4  tie count (int)
#define SM_LOSS 132100      //      4  block-local loss accumulator (f32)
#define SM_TIEL 132104      //  1,024  128 x uint2 tie entries
#define SM_TOT  133128      // -> 1 block/CU, 16 waves (4/SIMD)

typedef __attribute__((ext_vector_type(8)))  __bf16 bf16x8;
typedef __attribute__((ext_vector_type(8)))  short  s16x8;
typedef __attribute__((ext_vector_type(16))) float  f32x16;

__device__ __forceinline__ unsigned short f2bf(float f) {   // RNE fp32->bf16 bits
    unsigned u = __float_as_uint(f);
    u += 0x7FFFu + ((u >> 16) & 1u);
    return (unsigned short)(u >> 16);
}
__device__ __forceinline__ float bf2f(unsigned short h) {
    return __uint_as_float(((unsigned)h) << 16);
}
// BRANCHLESS top-3 insert (value-only; exact ties have gap 0 < THR and are
// resolved by the exact-fp64 refine which applies the smaller-k rule).
__device__ __forceinline__ void ins3(float& v1, int& k1, float& v2, int& k2,
                                     float& v3, int& k3, float v, int k) {
    bool b1 = v > v1, b2 = v > v2, b3 = v > v3;
    v3 = b2 ? v2 : (b3 ? v : v3);
    k3 = b2 ? k2 : (b3 ? k : k3);
    v2 = b1 ? v1 : (b2 ? v : v2);
    k2 = b1 ? k1 : (b2 ? k : k2);
    v1 = b1 ? v : v1;
    k1 = b1 ? k : k1;
}

// --- K0a: per-code squared norms, wave-parallel ---------------------------
__global__ __launch_bounds__(256) void esq_kernel(const float* __restrict__ E,
                                                  float* __restrict__ esq,
                                                  float* __restrict__ loss) {
    if (blockIdx.x == 0 && threadIdx.x == 0) loss[0] = 0.f;
    int k = blockIdx.x * 4 + (threadIdx.x >> 6);
    int lane = threadIdx.x & 63;
    const float* er = E + (size_t)k * D_DIM;
    float s = 0.f;
#pragma unroll
    for (int i = 0; i < 4; ++i) { float v = er[lane + 64 * i]; s = fmaf(v, v, s); }
#pragma unroll
    for (int off = 32; off > 0; off >>= 1) s += __shfl_down(s, off, 64);
    if (lane == 0) esq[k] = s;
}

// --- K0b: pre-pack E into MFMA A-frag order (bf16) ------------------------
// frag (kc, dc, lane): A[m=lane&31][kd=(lane>>5)*8+j], k=kc*32+m,
// d=dc*16+(lane>>5)*8+j. dc==16 = esq-fold: slot0=bf16(-esq/2), slot1=residual.
__global__ __launch_bounds__(256) void prepack_kernel(const float* __restrict__ E,
        const float* __restrict__ esq, unsigned short* __restrict__ Ehi) {
    int gid = blockIdx.x * 256 + threadIdx.x;        // == (kc*17+dc)*64 + lane
    if (gid >= 32 * NDC * 64) return;
    int lane = gid & 63;
    int dc = (gid >> 6) % NDC;
    int kc = gid / (NDC * 64);
    int m = lane & 31, dh = lane >> 5;
    int k = kc * 32 + m;
    unsigned short h8[8];
#pragma unroll
    for (int j = 0; j < 8; ++j) h8[j] = 0;
    if (dc < 16) {
        int d0 = dc * 16 + dh * 8;
        const float* ep = E + (size_t)k * D_DIM + d0;
#pragma unroll
        for (int j = 0; j < 8; ++j) h8[j] = f2bf(ep[j]);
    } else if (dh == 0) {
        float v = -0.5f * esq[k];
        unsigned short h = f2bf(v);
        h8[0] = h;
        h8[1] = f2bf(v - bf2f(h));
    }
    s16x8 hv;
#pragma unroll
    for (int j = 0; j < 8; ++j) hv[j] = (short)h8[j];
    ((s16x8*)Ehi)[gid] = hv;
}

// --- K1: fused main. grid 512, 1024 thr / 16 waves (4/SIMD) ---------------
// ATOMIC-SERIALIZATION FIX (session ledger, R11): at THR=0.6 ~21% of tokens
// are near-ties -> ~13,700 per-tie atomicAdd(loss) chip-wide on ONE address
// = ~170us of L2-bank-serialized RMWs (the "epilogue" cost in every round:
// R7-9 finish ~190us with atomics, R2/R4 gather-only ~10us without).
// Fix: Guideline 12 — accumulate the block's loss in ONE LDS float (LDS
// atomics: ~29/block, distributed), then a single global atomicAdd per
// block (512 total). Everything else identical to the verified R11 kernel.
__global__ __launch_bounds__(1024) void vq_main_kernel(
        const float* __restrict__ X, const unsigned short* __restrict__ Ehi,
        const float* __restrict__ E, float* __restrict__ out0,
        float* __restrict__ loss, float* __restrict__ idxf_out) {
    extern __shared__ char smem[];
    unsigned short* xhf = (unsigned short*)(smem + SM_XH);
    float* x2p = (float*)(smem + SM_X2P);
    float* redv = (float*)(smem + SM_RV);
    int*   redk = (int*)(smem + SM_RK);
    float* q    = (float*)(smem + SM_Q);     // overlay after main loop
    int*   idxs = (int*)(smem + SM_IDX);
    int*   tiec = (int*)(smem + SM_TIEC);
    float* lacc = (float*)(smem + SM_LOSS);  // block-local loss accumulator
    uint2* tiel = (uint2*)(smem + SM_TIEL);

    int tid = threadIdx.x;
    int lane = tid & 63;
    int w = tid >> 6;                        // 0..15
    int dhalf = lane >> 5;
    int b = blockIdx.x >> 4;                 // 16 tiles of 128 t per b
    int tg0 = (blockIdx.x & 15) << 7;

    if (tid == 0) { tiec[0] = 0; lacc[0] = 0.f; }

    // ---- stage X tile [128 t][256 d] -> frag-order bf16 + ||x||^2 ----
    {
        int t = tid & 127, dblk = tid >> 7;  // 8 dblk x 32 d
        int tc = t >> 5, m = t & 31;
        const float* xp = X + (size_t)b * ((size_t)D_DIM * T_SZ) + tg0 + t;
        float x2a = 0.f;
#pragma unroll
        for (int g = 0; g < 4; ++g) {
            int d0 = dblk * 32 + g * 8;
            s16x8 hv;
#pragma unroll
            for (int j = 0; j < 8; ++j) {
                float xv = __builtin_nontemporal_load(
                               &xp[(size_t)(d0 + j) * T_SZ]);
                hv[j] = (short)f2bf(xv);
                x2a = fmaf(xv, xv, x2a);
            }
            int fi = (tc * 16 + (d0 >> 4)) * 64 + ((d0 >> 3) & 1) * 32 + m;
            ((s16x8*)xhf)[fi] = hv;
        }
        x2p[tid] = x2a;
    }
    __syncthreads();

    const s16x8* ehp = (const s16x8*)Ehi;
    const s16x8* bhf = (const s16x8*)xhf;
    int kq = w >> 1;                         // 0..7
    int tcb = (w & 1) * 2;                   // tc pair {tcb, tcb+1}

    s16x8 bfold = {0, 0, 0, 0, 0, 0, 0, 0};
    if (dhalf == 0) { bfold[0] = (short)0x3F80; bfold[1] = (short)0x3F80; }
    bf16x8 bh_fold = __builtin_bit_cast(bf16x8, bfold);

    float v1s[2], v2s[2], v3s[2];
    int k1s[2], k2s[2], k3s[2];
#pragma unroll
    for (int j = 0; j < 2; ++j) { v1s[j] = -INFINITY; v2s[j] = -INFINITY;
                                  v3s[j] = -INFINITY; k1s[j] = 0; k2s[j] = 0;
                                  k3s[j] = 0; }

#pragma unroll 1
    for (int rnd = 0; rnd < 4; ++rnd) {
        int kc = rnd * 8 + kq;
        f32x16 acc0, acc1;
#pragma unroll
        for (int i = 0; i < 16; ++i) { acc0[i] = 0.f; acc1[i] = 0.f; }

        size_t ab = (size_t)kc * NDC * 64 + lane;
        s16x8 nh = ehp[ab];                  // depth-1 rotating E prefetch

#pragma unroll 1
        for (int dc = 0; dc < 16; ++dc) {
            bf16x8 ah = __builtin_bit_cast(bf16x8, nh);
            nh = ehp[ab + (size_t)(dc + 1) * 64];    // dc==15 -> fold chunk
            bf16x8 bh0 = __builtin_bit_cast(bf16x8, bhf[(tcb * 16 + dc) * 64 + lane]);
            bf16x8 bh1 = __builtin_bit_cast(bf16x8, bhf[((tcb + 1) * 16 + dc) * 64 + lane]);
            acc0 = __builtin_amdgcn_mfma_f32_32x32x16_bf16(ah, bh0, acc0, 0, 0, 0);
            acc1 = __builtin_amdgcn_mfma_f32_32x32x16_bf16(ah, bh1, acc1, 0, 0, 0);
        }
        {   // esq-fold chunk (dc==16, in nh): B constant 1.0 in kd slots 0,1
            bf16x8 ah = __builtin_bit_cast(bf16x8, nh);
            acc0 = __builtin_amdgcn_mfma_f32_32x32x16_bf16(ah, bh_fold, acc0, 0, 0, 0);
            acc1 = __builtin_amdgcn_mfma_f32_32x32x16_bf16(ah, bh_fold, acc1, 0, 0, 0);
        }
        // scan acc -> running top3 (branchless)
        int kb = kc * 32 + 4 * dhalf;
#pragma unroll
        for (int ri = 0; ri < 16; ++ri) {
            int kk = kb + (ri & 3) + 8 * (ri >> 2);
            ins3(v1s[0], k1s[0], v2s[0], k2s[0], v3s[0], k3s[0], acc0[ri], kk);
            ins3(v1s[1], k1s[1], v2s[1], k2s[1], v3s[1], k3s[1], acc1[ri], kk);
        }
    }

    // merge lane^32 partner (same t, complementary k rows), store to LDS
#pragma unroll
    for (int tcj = 0; tcj < 2; ++tcj) {
        float pv1 = __shfl_xor(v1s[tcj], 32, 64); int pk1 = __shfl_xor(k1s[tcj], 32, 64);
        float pv2 = __shfl_xor(v2s[tcj], 32, 64); int pk2 = __shfl_xor(k2s[tcj], 32, 64);
        float pv3 = __shfl_xor(v3s[tcj], 32, 64); int pk3 = __shfl_xor(k3s[tcj], 32, 64);
        ins3(v1s[tcj], k1s[tcj], v2s[tcj], k2s[tcj], v3s[tcj], k3s[tcj], pv1, pk1);
        ins3(v1s[tcj], k1s[tcj], v2s[tcj], k2s[tcj], v3s[tcj], k3s[tcj], pv2, pk2);
        ins3(v1s[tcj], k1s[tcj], v2s[tcj], k2s[tcj], v3s[tcj], k3s[tcj], pv3, pk3);
        if (dhalf == 0) {
            int base = ((w * 2 + tcj) * 32 + (lane & 31)) * 3;
            redv[base]     = v1s[tcj]; redk[base]     = k1s[tcj];
            redv[base + 1] = v2s[tcj]; redk[base + 1] = k2s[tcj];
            redv[base + 2] = v3s[tcj]; redk[base + 2] = k3s[tcj];
        }
    }
    __syncthreads();

    // per-t reduce across the 8 contributing waves; near-ties deferred.
    // Loss contributions go to the LDS accumulator (raw sums; scaled once).
    if (tid < 128) {
        int t = tid, tc = t >> 5, m = t & 31;
        int p = tc >> 1, tcj = tc & 1;       // wave parity / tcj for this tc
        float v1 = -INFINITY, v2 = -INFINITY, v3 = -INFINITY;
        int k1 = 0, k2 = 0, k3 = 0;
#pragma unroll
        for (int qq = 0; qq < 8; ++qq) {
            int ww = qq * 2 + p;
            int base = ((ww * 2 + tcj) * 32 + m) * 3;
            ins3(v1, k1, v2, k2, v3, k3, redv[base], redk[base]);
            ins3(v1, k1, v2, k2, v3, k3, redv[base + 1], redk[base + 1]);
            ins3(v1, k1, v2, k2, v3, k3, redv[base + 2], redk[base + 2]);
        }
        float dmin2 = 0.f;
        if (v1 - v2 < THR) {      // near-tie: defer exact fp64 refinement
            int slot = atomicAdd(tiec, 1);
            tiel[slot] = make_uint2(((unsigned)t << 10) | (unsigned)k1,
                                    ((unsigned)k2 << 16) | (unsigned)k3);
        } else {
            idxs[t] = k1;
            idxf_out[(size_t)b * T_SZ + tg0 + t] = (float)k1;
            float x2 = 0.f;
#pragma unroll
            for (int i = 0; i < 8; ++i) x2 += x2p[t + 128 * i];
            dmin2 = x2 - 2.0f * v1;   // ||x||^2 - 2(x.e - esq/2) = ||x-e||^2
        }
        float lsum = dmin2;
#pragma unroll
        for (int off = 32; off > 0; off >>= 1) lsum += __shfl_down(lsum, off, 64);
        if ((tid & 63) == 0) atomicAdd(lacc, lsum);      // LDS atomic (2/block)
    }
    __syncthreads();

    // wave-parallel exact refinement: one wave per tie, 64 lanes x 4 d each
    {
        int ntie = tiec[0];
        for (int e = w; e < ntie; e += 16) {
            uint2 pk = tiel[e];
            int t = pk.x >> 10;
            int k1 = pk.x & 1023, k2 = pk.y >> 16, k3 = pk.y & 1023;
            const float* e1 = E + (size_t)k1 * D_DIM;
            const float* e2 = E + (size_t)k2 * D_DIM;
            const float* e3 = E + (size_t)k3 * D_DIM;
            const float* xc = X + (size_t)b * ((size_t)D_DIM * T_SZ) + tg0 + t;
            int d0 = lane * 4;
            double d1 = 0.0, d2 = 0.0, d3 = 0.0;
#pragma unroll
            for (int u = 0; u < 4; ++u) {
                int d = d0 + u;
                double xd = (double)xc[(size_t)d * T_SZ];
                double u1 = xd - (double)e1[d];
                double u2 = xd - (double)e2[d];
                double u3 = xd - (double)e3[d];
                d1 += u1 * u1;
                d2 += u2 * u2;
                d3 += u3 * u3;
            }
#pragma unroll
            for (int off = 32; off > 0; off >>= 1) {
                d1 += __shfl_down(d1, off, 64);
                d2 += __shfl_down(d2, off, 64);
                d3 += __shfl_down(d3, off, 64);
            }
            if (lane == 0) {
                int kb = k1; double dm = d1;
                if (d2 < dm || (d2 == dm && k2 < kb)) { kb = k2; dm = d2; }
                if (d3 < dm || (d3 == dm && k3 < kb)) { kb = k3; dm = d3; }
                idxs[t] = kb;
                idxf_out[(size_t)b * T_SZ + tg0 + t] = (float)kb;
                atomicAdd(lacc, (float)dm);              // LDS atomic (~27/block)
            }
        }
    }
    __syncthreads();

    // ONE global loss atomic per block (512 total vs ~14K per-tie before)
    if (tid == 0) atomicAdd(loss, lacc[0] * (0.5f / (float)TOT));

    // gather E rows into q overlay (stride 257 -> conflict-free column reads)
    {
        for (int i = 0; i < 8; ++i) {
            int r = w * 8 + i;
            int row = idxs[r];
            const float* ep = E + (size_t)row * D_DIM;
#pragma unroll
            for (int u = 0; u < 4; ++u)
                q[r * 257 + lane + 64 * u] = ep[lane + 64 * u];
        }
    }
    __syncthreads();

    // write out0 [B,D,T]: NT stores; lanes over t (coalesced 256B)
    {
        int t = tid & 127, dgrp = tid >> 7;
        size_t obase = (size_t)b * ((size_t)D_DIM * T_SZ) + tg0 + t;
#pragma unroll 8
        for (int j = 0; j < 32; ++j) {
            int d = dgrp * 32 + j;
            __builtin_nontemporal_store(q[t * 257 + d],
                                        &out0[obase + (size_t)d * T_SZ]);
        }
    }
}

extern "C" void kernel_launch(void* const* d_in, const int* in_sizes, int n_in,
                              void* d_out, int out_size, void* d_ws, size_t ws_size,
                              hipStream_t stream) {
    const float* X = (const float*)d_in[0];   // [32, 256, 2048] fp32
    const float* E = (const float*)d_in[1];   // [1024, 256] fp32
    float* out = (float*)d_out;
    float* loss = out + LOSS_OFF;
    float* idxf = out + IDX_OFF;

    float*          esq = (float*)((char*)d_ws + WS_ESQ);
    unsigned short* Ehi = (unsigned short*)((char*)d_ws + WS_EHI);

    esq_kernel<<<K_EMB / 4, 256, 0, stream>>>(E, esq, loss);
    prepack_kernel<<<(32 * NDC * 64 + 255) / 256, 256, 0, stream>>>(E, esq, Ehi);
    vq_main_kernel<<<512, 1024, SM_TOT, stream>>>(X, Ehi, E, out, loss, idxf);
}

// Round 13
// 190.588 us; speedup vs baseline: 3.5958x; 1.0252x over previous
//
#include <hip/hip_runtime.h>
#include <math.h>

#define K_EMB 1024
#define D_DIM 256
#define T_SZ 2048
#define TOT 16777216        // B*D*T
#define LOSS_OFF 16777216
#define IDX_OFF 16777217
#define NDC 17              // 16 real d-chunks + 1 esq-fold chunk (A-side)
#define THR 0.6f            // ~10 sigma of bf16 score-diff noise -> exact refine

// workspace layout (bytes)
#define WS_ESQ  0           //     4,096  per-code ||e||^2
#define WS_EHI  4096        //   557,056  E frags [32 kc][17 dc][64 lane] x 16B

// vq_main LDS (bytes) — 66,568 total -> 2 blocks/CU (the R12->R13 lever:
// one block's mem-bound stage/epilogue overlaps the other's MFMA+VALU loop)
#define SM_XH   0           // 32,768  x frags: [tc2][dc16][64 lane][16B]
#define SM_X2P  32768       //  2,048  per-thread x^2 partials (512 f32)
#define SM_RV   34816       //  6,144  top3 vals [8w][2tcj][32m][3]
#define SM_RK   40960       //  6,144  top3 keys
#define SM_Q    0           // overlay after main: 64 rows x 257 f32 = 65,792
#define SM_IDX  65792       //    256  idx per t (above overlay, live to end)
#define SM_TIEC 66048       //      4  tie count (int)
#define SM_LOSS 66052       //      4  block-local loss accumulator (f32)
#define SM_TIEL 66056       //    512  64 x uint2 tie entries
#define SM_TOT  66568

typedef __attribute__((ext_vector_type(8)))  __bf16 bf16x8;
typedef __attribute__((ext_vector_type(8)))  short  s16x8;
typedef __attribute__((ext_vector_type(16))) float  f32x16;

__device__ __forceinline__ unsigned short f2bf(float f) {   // RNE fp32->bf16 bits
    unsigned u = __float_as_uint(f);
    u += 0x7FFFu + ((u >> 16) & 1u);
    return (unsigned short)(u >> 16);
}
__device__ __forceinline__ float bf2f(unsigned short h) {
    return __uint_as_float(((unsigned)h) << 16);
}
// BRANCHLESS top-3 insert (value-only; exact ties have gap 0 < THR and are
// resolved by the exact-fp64 refine which applies the smaller-k rule).
__device__ __forceinline__ void ins3(float& v1, int& k1, float& v2, int& k2,
                                     float& v3, int& k3, float v, int k) {
    bool b1 = v > v1, b2 = v > v2, b3 = v > v3;
    v3 = b2 ? v2 : (b3 ? v : v3);
    k3 = b2 ? k2 : (b3 ? k : k3);
    v2 = b1 ? v1 : (b2 ? v : v2);
    k2 = b1 ? k1 : (b2 ? k : k2);
    v1 = b1 ? v : v1;
    k1 = b1 ? k : k1;
}

// --- K0a: per-code squared norms, wave-parallel ---------------------------
__global__ __launch_bounds__(256) void esq_kernel(const float* __restrict__ E,
                                                  float* __restrict__ esq,
                                                  float* __restrict__ loss) {
    if (blockIdx.x == 0 && threadIdx.x == 0) loss[0] = 0.f;
    int k = blockIdx.x * 4 + (threadIdx.x >> 6);
    int lane = threadIdx.x & 63;
    const float* er = E + (size_t)k * D_DIM;
    float s = 0.f;
#pragma unroll
    for (int i = 0; i < 4; ++i) { float v = er[lane + 64 * i]; s = fmaf(v, v, s); }
#pragma unroll
    for (int off = 32; off > 0; off >>= 1) s += __shfl_down(s, off, 64);
    if (lane == 0) esq[k] = s;
}

// --- K0b: pre-pack E into MFMA A-frag order (bf16) ------------------------
// frag (kc, dc, lane): A[m=lane&31][kd=(lane>>5)*8+j], k=kc*32+m,
// d=dc*16+(lane>>5)*8+j. dc==16 = esq-fold: slot0=bf16(-esq/2), slot1=residual.
__global__ __launch_bounds__(256) void prepack_kernel(const float* __restrict__ E,
        const float* __restrict__ esq, unsigned short* __restrict__ Ehi) {
    int gid = blockIdx.x * 256 + threadIdx.x;        // == (kc*17+dc)*64 + lane
    if (gid >= 32 * NDC * 64) return;
    int lane = gid & 63;
    int dc = (gid >> 6) % NDC;
    int kc = gid / (NDC * 64);
    int m = lane & 31, dh = lane >> 5;
    int k = kc * 32 + m;
    unsigned short h8[8];
#pragma unroll
    for (int j = 0; j < 8; ++j) h8[j] = 0;
    if (dc < 16) {
        int d0 = dc * 16 + dh * 8;
        const float* ep = E + (size_t)k * D_DIM + d0;
#pragma unroll
        for (int j = 0; j < 8; ++j) h8[j] = f2bf(ep[j]);
    } else if (dh == 0) {
        float v = -0.5f * esq[k];
        unsigned short h = f2bf(v);
        h8[0] = h;
        h8[1] = f2bf(v - bf2f(h));
    }
    s16x8 hv;
#pragma unroll
    for (int j = 0; j < 8; ++j) hv[j] = (short)h8[j];
    ((s16x8*)Ehi)[gid] = hv;
}

// --- K1: fused main. grid 1024, 512 thr / 8 waves, 2 BLOCKS/CU ------------
// Same verified pipeline as R12 (which fixed the loss-atomic serialization),
// shrunk to t-tile 64 / 67KB LDS so two blocks co-reside per CU: block A's
// memory phases (X-stage ~15us, gather/out ~10us) overlap block B's
// MFMA+scan loop. Wave w owns kc = rnd*8+w over 4 rounds, acc[2 tcj] = 32
// AGPR (~84 regs total, no spill at the 128-reg budget of lb(512,2)).
__global__ __launch_bounds__(512, 2) void vq_main_kernel(
        const float* __restrict__ X, const unsigned short* __restrict__ Ehi,
        const float* __restrict__ E, float* __restrict__ out0,
        float* __restrict__ loss, float* __restrict__ idxf_out) {
    extern __shared__ char smem[];
    unsigned short* xhf = (unsigned short*)(smem + SM_XH);
    float* x2p = (float*)(smem + SM_X2P);
    float* redv = (float*)(smem + SM_RV);
    int*   redk = (int*)(smem + SM_RK);
    float* q    = (float*)(smem + SM_Q);     // overlay after main loop
    int*   idxs = (int*)(smem + SM_IDX);
    int*   tiec = (int*)(smem + SM_TIEC);
    float* lacc = (float*)(smem + SM_LOSS);  // block-local loss accumulator
    uint2* tiel = (uint2*)(smem + SM_TIEL);

    int tid = threadIdx.x;
    int lane = tid & 63;
    int w = tid >> 6;                        // 0..7
    int dhalf = lane >> 5;
    int b = blockIdx.x >> 5;                 // 32 tiles of 64 t per b
    int tg0 = (blockIdx.x & 31) << 6;

    if (tid == 0) { tiec[0] = 0; lacc[0] = 0.f; }

    // ---- stage X tile [64 t][256 d] -> frag-order bf16 + ||x||^2 ----
    {
        int t = tid & 63, dblk = tid >> 6;   // 8 dblk x 32 d
        int tc = t >> 5, m = t & 31;
        const float* xp = X + (size_t)b * ((size_t)D_DIM * T_SZ) + tg0 + t;
        float x2a = 0.f;
#pragma unroll
        for (int g = 0; g < 4; ++g) {
            int d0 = dblk * 32 + g * 8;
            s16x8 hv;
#pragma unroll
            for (int j = 0; j < 8; ++j) {
                float xv = __builtin_nontemporal_load(
                               &xp[(size_t)(d0 + j) * T_SZ]);
                hv[j] = (short)f2bf(xv);
                x2a = fmaf(xv, xv, x2a);
            }
            int fi = (tc * 16 + (d0 >> 4)) * 64 + ((d0 >> 3) & 1) * 32 + m;
            ((s16x8*)xhf)[fi] = hv;
        }
        x2p[tid] = x2a;
    }
    __syncthreads();

    const s16x8* ehp = (const s16x8*)Ehi;
    const s16x8* bhf = (const s16x8*)xhf;

    s16x8 bfold = {0, 0, 0, 0, 0, 0, 0, 0};
    if (dhalf == 0) { bfold[0] = (short)0x3F80; bfold[1] = (short)0x3F80; }
    bf16x8 bh_fold = __builtin_bit_cast(bf16x8, bfold);

    float v1s[2], v2s[2], v3s[2];
    int k1s[2], k2s[2], k3s[2];
#pragma unroll
    for (int j = 0; j < 2; ++j) { v1s[j] = -INFINITY; v2s[j] = -INFINITY;
                                  v3s[j] = -INFINITY; k1s[j] = 0; k2s[j] = 0;
                                  k3s[j] = 0; }

#pragma unroll 1
    for (int rnd = 0; rnd < 4; ++rnd) {
        int kc = rnd * 8 + w;                // this wave's codebook tile
        f32x16 acc0, acc1;
#pragma unroll
        for (int i = 0; i < 16; ++i) { acc0[i] = 0.f; acc1[i] = 0.f; }

        size_t ab = (size_t)kc * NDC * 64 + lane;
        s16x8 nh = ehp[ab];                  // depth-1 rotating E prefetch

#pragma unroll 1
        for (int dc = 0; dc < 16; ++dc) {
            bf16x8 ah = __builtin_bit_cast(bf16x8, nh);
            nh = ehp[ab + (size_t)(dc + 1) * 64];    // dc==15 -> fold chunk
            bf16x8 bh0 = __builtin_bit_cast(bf16x8, bhf[dc * 64 + lane]);
            bf16x8 bh1 = __builtin_bit_cast(bf16x8, bhf[(16 + dc) * 64 + lane]);
            acc0 = __builtin_amdgcn_mfma_f32_32x32x16_bf16(ah, bh0, acc0, 0, 0, 0);
            acc1 = __builtin_amdgcn_mfma_f32_32x32x16_bf16(ah, bh1, acc1, 0, 0, 0);
        }
        {   // esq-fold chunk (dc==16, in nh): B constant 1.0 in kd slots 0,1
            bf16x8 ah = __builtin_bit_cast(bf16x8, nh);
            acc0 = __builtin_amdgcn_mfma_f32_32x32x16_bf16(ah, bh_fold, acc0, 0, 0, 0);
            acc1 = __builtin_amdgcn_mfma_f32_32x32x16_bf16(ah, bh_fold, acc1, 0, 0, 0);
        }
        // scan acc -> running top3 (branchless)
        int kb = kc * 32 + 4 * dhalf;
#pragma unroll
        for (int ri = 0; ri < 16; ++ri) {
            int kk = kb + (ri & 3) + 8 * (ri >> 2);
            ins3(v1s[0], k1s[0], v2s[0], k2s[0], v3s[0], k3s[0], acc0[ri], kk);
            ins3(v1s[1], k1s[1], v2s[1], k2s[1], v3s[1], k3s[1], acc1[ri], kk);
        }
    }

    // merge lane^32 partner (same t, complementary k rows), store to LDS
#pragma unroll
    for (int tcj = 0; tcj < 2; ++tcj) {
        float pv1 = __shfl_xor(v1s[tcj], 32, 64); int pk1 = __shfl_xor(k1s[tcj], 32, 64);
        float pv2 = __shfl_xor(v2s[tcj], 32, 64); int pk2 = __shfl_xor(k2s[tcj], 32, 64);
        float pv3 = __shfl_xor(v3s[tcj], 32, 64); int pk3 = __shfl_xor(k3s[tcj], 32, 64);
        ins3(v1s[tcj], k1s[tcj], v2s[tcj], k2s[tcj], v3s[tcj], k3s[tcj], pv1, pk1);
        ins3(v1s[tcj], k1s[tcj], v2s[tcj], k2s[tcj], v3s[tcj], k3s[tcj], pv2, pk2);
        ins3(v1s[tcj], k1s[tcj], v2s[tcj], k2s[tcj], v3s[tcj], k3s[tcj], pv3, pk3);
        if (dhalf == 0) {
            int base = ((w * 2 + tcj) * 32 + (lane & 31)) * 3;
            redv[base]     = v1s[tcj]; redk[base]     = k1s[tcj];
            redv[base + 1] = v2s[tcj]; redk[base + 1] = k2s[tcj];
            redv[base + 2] = v3s[tcj]; redk[base + 2] = k3s[tcj];
        }
    }
    __syncthreads();

    // per-t reduce across 8 waves; near-ties deferred; loss -> LDS acc
    if (tid < 64) {
        int t = tid, tcj = t >> 5, m = t & 31;
        float v1 = -INFINITY, v2 = -INFINITY, v3 = -INFINITY;
        int k1 = 0, k2 = 0, k3 = 0;
#pragma unroll
        for (int ww = 0; ww < 8; ++ww) {
            int base = ((ww * 2 + tcj) * 32 + m) * 3;
            ins3(v1, k1, v2, k2, v3, k3, redv[base], redk[base]);
            ins3(v1, k1, v2, k2, v3, k3, redv[base + 1], redk[base + 1]);
            ins3(v1, k1, v2, k2, v3, k3, redv[base + 2], redk[base + 2]);
        }
        float dmin2 = 0.f;
        if (v1 - v2 < THR) {      // near-tie: defer exact fp64 refinement
            int slot = atomicAdd(tiec, 1);
            tiel[slot] = make_uint2(((unsigned)t << 10) | (unsigned)k1,
                                    ((unsigned)k2 << 16) | (unsigned)k3);
        } else {
            idxs[t] = k1;
            idxf_out[(size_t)b * T_SZ + tg0 + t] = (float)k1;
            float x2 = 0.f;
#pragma unroll
            for (int i = 0; i < 8; ++i) x2 += x2p[t + 64 * i];
            dmin2 = x2 - 2.0f * v1;   // ||x||^2 - 2(x.e - esq/2) = ||x-e||^2
        }
        float lsum = dmin2;
#pragma unroll
        for (int off = 32; off > 0; off >>= 1) lsum += __shfl_down(lsum, off, 64);
        if (tid == 0) atomicAdd(lacc, lsum);             // LDS atomic
    }
    __syncthreads();

    // wave-parallel exact refinement: one wave per tie, 64 lanes x 4 d each
    {
        int ntie = tiec[0];
        for (int e = w; e < ntie; e += 8) {
            uint2 pk = tiel[e];
            int t = pk.x >> 10;
            int k1 = pk.x & 1023, k2 = pk.y >> 16, k3 = pk.y & 1023;
            const float* e1 = E + (size_t)k1 * D_DIM;
            const float* e2 = E + (size_t)k2 * D_DIM;
            const float* e3 = E + (size_t)k3 * D_DIM;
            const float* xc = X + (size_t)b * ((size_t)D_DIM * T_SZ) + tg0 + t;
            int d0 = lane * 4;
            double d1 = 0.0, d2 = 0.0, d3 = 0.0;
#pragma unroll
            for (int u = 0; u < 4; ++u) {
                int d = d0 + u;
                double xd = (double)xc[(size_t)d * T_SZ];
                double u1 = xd - (double)e1[d];
                double u2 = xd - (double)e2[d];
                double u3 = xd - (double)e3[d];
                d1 += u1 * u1;
                d2 += u2 * u2;
                d3 += u3 * u3;
            }
#pragma unroll
            for (int off = 32; off > 0; off >>= 1) {
                d1 += __shfl_down(d1, off, 64);
                d2 += __shfl_down(d2, off, 64);
                d3 += __shfl_down(d3, off, 64);
            }
            if (lane == 0) {
                int kb = k1; double dm = d1;
                if (d2 < dm || (d2 == dm && k2 < kb)) { kb = k2; dm = d2; }
                if (d3 < dm || (d3 == dm && k3 < kb)) { kb = k3; dm = d3; }
                idxs[t] = kb;
                idxf_out[(size_t)b * T_SZ + tg0 + t] = (float)kb;
                atomicAdd(lacc, (float)dm);              // LDS atomic
            }
        }
    }
    __syncthreads();

    // ONE global loss atomic per block (1024 total; distributed, cheap)
    if (tid == 0) atomicAdd(loss, lacc[0] * (0.5f / (float)TOT));

    // gather E rows into q overlay (stride 257 -> conflict-free column reads)
    {
        for (int i = 0; i < 8; ++i) {
            int r = w * 8 + i;
            int row = idxs[r];
            const float* ep = E + (size_t)row * D_DIM;
#pragma unroll
            for (int u = 0; u < 4; ++u)
                q[r * 257 + lane + 64 * u] = ep[lane + 64 * u];
        }
    }
    __syncthreads();

    // write out0 [B,D,T]: NT stores; lanes over t (coalesced 256B)
    {
        int t = tid & 63, dgrp = tid >> 6;
        size_t obase = (size_t)b * ((size_t)D_DIM * T_SZ) + tg0 + t;
#pragma unroll 8
        for (int j = 0; j < 32; ++j) {
            int d = dgrp * 32 + j;
            __builtin_nontemporal_store(q[t * 257 + d],
                                        &out0[obase + (size_t)d * T_SZ]);
        }
    }
}

extern "C" void kernel_launch(void* const* d_in, const int* in_sizes, int n_in,
                              void* d_out, int out_size, void* d_ws, size_t ws_size,
                              hipStream_t stream) {
    const float* X = (const float*)d_in[0];   // [32, 256, 2048] fp32
    const float* E = (const float*)d_in[1];   // [1024, 256] fp32
    float* out = (float*)d_out;
    float* loss = out + LOSS_OFF;
    float* idxf = out + IDX_OFF;

    float*          esq = (float*)((char*)d_ws + WS_ESQ);
    unsigned short* Ehi = (unsigned short*)((char*)d_ws + WS_EHI);

    esq_kernel<<<K_EMB / 4, 256, 0, stream>>>(E, esq, loss);
    prepack_kernel<<<(32 * NDC * 64 + 255) / 256, 256, 0, stream>>>(E, esq, Ehi);
    vq_main_kernel<<<1024, 512, SM_TOT, stream>>>(X, Ehi, E, out, loss, idxf);
}